// Round 1
// baseline (531.962 us; speedup 1.0000x reference)
//
#include <hip/hip_runtime.h>
#include <hip/hip_bf16.h>

// GQA block for MI355X. bf16 MFMA (16x16x32), fp32 accumulation.
// Requires ws_size >= 60 MB.
//
// Pipeline:
//   cvt X -> bf16                       (Xb)
//   transpose+cvt Wq/Wk/Wv/Wo -> [N,K] bf16
//   gemm: Qb = Xb @ Wq + bq   [4096,2048] bf16
//   gemm: Kb = Xb @ Wk + bk   [4096, 512] bf16
//   gemm: Vt = (Xb @ Wv + bv)^T  [512,4096] bf16 (transposed store for PV B-operand)
//   flash attention (64 q-rows/block, online softmax) -> Ab (aliases Xb)
//   gemm: out = Ab @ Wo + bo  [4096,2048] fp32 -> d_out

typedef __attribute__((ext_vector_type(8))) short short8;
typedef __attribute__((ext_vector_type(4))) short short4v;
typedef __attribute__((ext_vector_type(4))) float float4v;

__device__ __forceinline__ short f2bf(float x) {
    __hip_bfloat16 h = __float2bfloat16(x);
    short s;
    __builtin_memcpy(&s, &h, sizeof(s));
    return s;
}

// ---------------- fp32 -> bf16 elementwise ----------------
__global__ __launch_bounds__(256) void cvt_bf16_kernel(const float* __restrict__ in,
                                                       short* __restrict__ out, int n) {
    int i = (blockIdx.x * 256 + threadIdx.x) * 4;
    if (i >= n) return;
    float4 v = *(const float4*)(in + i);
    short4v o;
    o[0] = f2bf(v.x); o[1] = f2bf(v.y); o[2] = f2bf(v.z); o[3] = f2bf(v.w);
    *(short4v*)(out + i) = o;
}

// ---------------- W[K,N] fp32 -> Wt[N,K] bf16 ----------------
__global__ __launch_bounds__(256) void transpose_cvt_kernel(const float* __restrict__ W,
                                                            short* __restrict__ Wt,
                                                            int K, int N) {
    __shared__ float tile[32][33];
    int n0 = blockIdx.x * 32, k0 = blockIdx.y * 32;
    int tx = threadIdx.x & 31, ty = threadIdx.x >> 5;  // ty 0..7
#pragma unroll
    for (int i = 0; i < 4; ++i) {
        int kk = ty + i * 8;
        tile[kk][tx] = W[(size_t)(k0 + kk) * N + n0 + tx];
    }
    __syncthreads();
#pragma unroll
    for (int i = 0; i < 4; ++i) {
        int nn = ty + i * 8;
        Wt[(size_t)(n0 + nn) * K + k0 + tx] = f2bf(tile[tx][nn]);
    }
}

// ---------------- GEMM: C[M,N] = A[M,K] @ Bt[N,K]^T + bias ----------------
// 128x128 tile, BK=32, 256 threads (4 waves, each 64x64).
// mode 0: bf16 C[M,N]; mode 1: bf16 C^T stored [N,M]; mode 2: fp32 C[M,N].
__global__ __launch_bounds__(256) void gemm_bt_kernel(
    const short* __restrict__ A, const short* __restrict__ Bt,
    const float* __restrict__ bias,
    short* __restrict__ Cb, float* __restrict__ Cf,
    int M, int N, int K, int mode) {
    __shared__ short As[128 * 32];
    __shared__ short Bs[128 * 32];
    const int t = threadIdx.x;
    const int lane = t & 63;
    const int l15 = lane & 15, quad = lane >> 4;
    const int wave = t >> 6;
    const int wm = (wave & 1) * 64, wn = (wave >> 1) * 64;
    const int m0 = blockIdx.y * 128, n0 = blockIdx.x * 128;
    const int sr = t >> 2;          // staging row 0..63 (+64 for 2nd chunk)
    const int sk = (t & 3) * 8;     // staging k-offset

    float4v acc[4][4] = {};

    for (int k0 = 0; k0 < K; k0 += 32) {
        short8 av0 = *(const short8*)(A + (size_t)(m0 + sr) * K + k0 + sk);
        short8 av1 = *(const short8*)(A + (size_t)(m0 + 64 + sr) * K + k0 + sk);
        short8 bv0 = *(const short8*)(Bt + (size_t)(n0 + sr) * K + k0 + sk);
        short8 bv1 = *(const short8*)(Bt + (size_t)(n0 + 64 + sr) * K + k0 + sk);
        __syncthreads();
        *(short8*)(As + sr * 32 + sk) = av0;
        *(short8*)(As + (64 + sr) * 32 + sk) = av1;
        *(short8*)(Bs + sr * 32 + sk) = bv0;
        *(short8*)(Bs + (64 + sr) * 32 + sk) = bv1;
        __syncthreads();
        short8 af[4], bfr[4];
#pragma unroll
        for (int i = 0; i < 4; ++i)
            af[i] = *(const short8*)(As + (wm + i * 16 + l15) * 32 + quad * 8);
#pragma unroll
        for (int j = 0; j < 4; ++j)
            bfr[j] = *(const short8*)(Bs + (wn + j * 16 + l15) * 32 + quad * 8);
#pragma unroll
        for (int i = 0; i < 4; ++i)
#pragma unroll
            for (int j = 0; j < 4; ++j)
                acc[i][j] = __builtin_amdgcn_mfma_f32_16x16x32_bf16(af[i], bfr[j], acc[i][j], 0, 0, 0);
    }

#pragma unroll
    for (int i = 0; i < 4; ++i)
#pragma unroll
        for (int j = 0; j < 4; ++j) {
            const int col = n0 + wn + j * 16 + l15;
            const float bc = bias[col];
#pragma unroll
            for (int r = 0; r < 4; ++r) {
                const int row = m0 + wm + i * 16 + quad * 4 + r;
                const float v = acc[i][j][r] + bc;
                if (mode == 0)      Cb[(size_t)row * N + col] = f2bf(v);
                else if (mode == 1) Cb[(size_t)col * M + row] = f2bf(v);
                else                Cf[(size_t)row * N + col] = v;
            }
        }
}

// ---------------- Flash attention ----------------
// grid (S/64, H, B), 256 threads. Each wave owns 16 q-rows.
// Qb [4096,2048], Kb [4096,512], Vt [512,4096], Ab [4096,2048].
// group = h % 4 (jnp.tile / torch .repeat semantics).
#define ATT_SCALE 0.08838834764831843f

__global__ __launch_bounds__(256) void flash_kernel(
    const short* __restrict__ Qb, const short* __restrict__ Kb,
    const short* __restrict__ Vt, const int* __restrict__ mask,
    short* __restrict__ Ab) {
    // padded strides (136 / 72) keep ds_read_b128 at free 2-way conflicts
    __shared__ short Ks[64 * 136];
    __shared__ short Vs[128 * 72];
    __shared__ short Ps[4 * 16 * 72];
    __shared__ float mb[64];

    const int t = threadIdx.x;
    const int lane = t & 63, wave = t >> 6;
    const int l15 = lane & 15, quad = lane >> 4;
    const int qt = blockIdx.x, h = blockIdx.y, b = blockIdx.z;
    const int g = h & 3;

    // Q fragments: A[m=l15][k=quad*8+j], 4 k-steps of 32
    short8 qf[4];
    const size_t qrow = (size_t)(b * 2048 + qt * 64 + wave * 16 + l15);
    const short* qp = Qb + qrow * 2048 + h * 128 + quad * 8;
#pragma unroll
    for (int ks = 0; ks < 4; ++ks) qf[ks] = *(const short8*)(qp + ks * 32);

    float4v o[8] = {};
    float m_i[4] = {-1e30f, -1e30f, -1e30f, -1e30f};
    float l_i[4] = {0.f, 0.f, 0.f, 0.f};

    const int kr = t >> 4, kc = (t & 15) * 8;  // K staging
    const int vr = t >> 3, vc = (t & 7) * 8;   // V staging

    for (int kt = 0; kt < 32; ++kt) {
        const int kbase = kt * 64;
        __syncthreads();
#pragma unroll
        for (int it = 0; it < 4; ++it) {
            int r = kr + it * 16;
            short8 v = *(const short8*)(Kb + (size_t)(b * 2048 + kbase + r) * 512 + g * 128 + kc);
            *(short8*)(Ks + r * 136 + kc) = v;
        }
#pragma unroll
        for (int it = 0; it < 4; ++it) {
            int r = vr + it * 32;
            short8 v = *(const short8*)(Vt + (size_t)(g * 128 + r) * 4096 + b * 2048 + kbase + vc);
            *(short8*)(Vs + r * 72 + vc) = v;
        }
        if (t < 64) mb[t] = mask[b * 2048 + kbase + t] ? 0.f : -1e30f;
        __syncthreads();

        // S = Q @ K^T : rows q (quad*4+r), cols key (j*16+l15)
        float4v s[4] = {};
#pragma unroll
        for (int ks = 0; ks < 4; ++ks)
#pragma unroll
            for (int j = 0; j < 4; ++j) {
                short8 bk = *(const short8*)(Ks + (j * 16 + l15) * 136 + ks * 32 + quad * 8);
                s[j] = __builtin_amdgcn_mfma_f32_16x16x32_bf16(qf[ks], bk, s[j], 0, 0, 0);
            }
#pragma unroll
        for (int j = 0; j < 4; ++j) {
            const float bias = mb[j * 16 + l15];
#pragma unroll
            for (int r = 0; r < 4; ++r) s[j][r] = s[j][r] * ATT_SCALE + bias;
        }
        // online softmax per row (row = quad*4+r; reduce across 16 lanes)
#pragma unroll
        for (int r = 0; r < 4; ++r) {
            float mx = fmaxf(fmaxf(s[0][r], s[1][r]), fmaxf(s[2][r], s[3][r]));
#pragma unroll
            for (int off = 1; off < 16; off <<= 1) mx = fmaxf(mx, __shfl_xor(mx, off, 64));
            const float mnew = fmaxf(m_i[r], mx);
            const float alpha = __expf(m_i[r] - mnew);
            m_i[r] = mnew;
            float rs = 0.f;
#pragma unroll
            for (int j = 0; j < 4; ++j) {
                float p = __expf(s[j][r] - mnew);
                s[j][r] = p;
                rs += p;
            }
#pragma unroll
            for (int off = 1; off < 16; off <<= 1) rs += __shfl_xor(rs, off, 64);
            l_i[r] = l_i[r] * alpha + rs;
#pragma unroll
            for (int jj = 0; jj < 8; ++jj) o[jj][r] *= alpha;
        }
        // P: C-layout -> A-layout via LDS round-trip (per-wave slice)
#pragma unroll
        for (int j = 0; j < 4; ++j)
#pragma unroll
            for (int r = 0; r < 4; ++r)
                Ps[wave * 1152 + (quad * 4 + r) * 72 + j * 16 + l15] = f2bf(s[j][r]);
        __syncthreads();
        // O += P @ V : B-operand from Vt tile (n=dd, k=key)
#pragma unroll
        for (int ks2 = 0; ks2 < 2; ++ks2) {
            short8 pa = *(const short8*)(Ps + wave * 1152 + l15 * 72 + ks2 * 32 + quad * 8);
#pragma unroll
            for (int jj = 0; jj < 8; ++jj) {
                short8 bv = *(const short8*)(Vs + (jj * 16 + l15) * 72 + ks2 * 32 + quad * 8);
                o[jj] = __builtin_amdgcn_mfma_f32_16x16x32_bf16(pa, bv, o[jj], 0, 0, 0);
            }
        }
    }

    float rl[4];
#pragma unroll
    for (int r = 0; r < 4; ++r) rl[r] = (l_i[r] > 0.f) ? 1.0f / l_i[r] : 0.f;
    const size_t orow = (size_t)(b * 2048 + qt * 64 + wave * 16);
#pragma unroll
    for (int jj = 0; jj < 8; ++jj)
#pragma unroll
        for (int r = 0; r < 4; ++r)
            Ab[(orow + quad * 4 + r) * 2048 + h * 128 + jj * 16 + l15] = f2bf(o[jj][r] * rl[r]);
}

extern "C" void kernel_launch(void* const* d_in, const int* in_sizes, int n_in,
                              void* d_out, int out_size, void* d_ws, size_t ws_size,
                              hipStream_t stream) {
    (void)in_sizes; (void)n_in; (void)out_size; (void)ws_size;
    const float* X  = (const float*)d_in[0];
    const int* mask = (const int*)d_in[1];
    const float* Wq = (const float*)d_in[2];
    const float* bq = (const float*)d_in[3];
    const float* Wk = (const float*)d_in[4];
    const float* bk = (const float*)d_in[5];
    const float* Wv = (const float*)d_in[6];
    const float* bv = (const float*)d_in[7];
    const float* Wo = (const float*)d_in[8];
    const float* bo = (const float*)d_in[9];
    float* out = (float*)d_out;

    char* ws = (char*)d_ws;
    short* Xb  = (short*)(ws + 0);          // 16,777,216 B  [reused as Ab]
    short* Wqt = (short*)(ws + 16777216);   //  8,388,608 B
    short* Wkt = (short*)(ws + 25165824);   //  2,097,152 B
    short* Wvt = (short*)(ws + 27262976);   //  2,097,152 B
    short* Wot = (short*)(ws + 29360128);   //  8,388,608 B
    short* Qb  = (short*)(ws + 37748736);   // 16,777,216 B
    short* Kb  = (short*)(ws + 54525952);   //  4,194,304 B
    short* Vtb = (short*)(ws + 58720256);   //  4,194,304 B
    short* Ab  = Xb;                        // Xb dead after V projection

    const int M = 4096, HID = 2048, KV = 512;

    cvt_bf16_kernel<<<8192, 256, 0, stream>>>(X, Xb, M * HID);
    transpose_cvt_kernel<<<dim3(64, 64), 256, 0, stream>>>(Wq, Wqt, HID, HID);
    transpose_cvt_kernel<<<dim3(16, 64), 256, 0, stream>>>(Wk, Wkt, HID, KV);
    transpose_cvt_kernel<<<dim3(16, 64), 256, 0, stream>>>(Wv, Wvt, HID, KV);
    transpose_cvt_kernel<<<dim3(64, 64), 256, 0, stream>>>(Wo, Wot, HID, HID);

    gemm_bt_kernel<<<dim3(16, 32), 256, 0, stream>>>(Xb, Wqt, bq, Qb, nullptr, M, HID, HID, 0);
    gemm_bt_kernel<<<dim3(4, 32), 256, 0, stream>>>(Xb, Wkt, bk, Kb, nullptr, M, KV, HID, 0);
    gemm_bt_kernel<<<dim3(4, 32), 256, 0, stream>>>(Xb, Wvt, bv, Vtb, nullptr, M, KV, HID, 1);

    flash_kernel<<<dim3(32, 16, 2), 256, 0, stream>>>(Qb, Kb, Vtb, mask, Ab);

    gemm_bt_kernel<<<dim3(16, 32), 256, 0, stream>>>(Ab, Wot, bo, nullptr, out, M, HID, HID, 2);
}

// Round 2
// 345.965 us; speedup vs baseline: 1.5376x; 1.5376x over previous
//
#include <hip/hip_runtime.h>
#include <hip/hip_bf16.h>

// GQA block for MI355X. bf16 MFMA 16x16x32, fp32 accumulation.
// Pipeline:
//   cvt X -> bf16 (Xb)
//   transpose+cvt [Wq|Wk|Wv] -> fused WqkvT [3072,2048] bf16 ; Wo -> Wot [2048,2048]
//   fused gemm (global_load_lds staging): Qb [4096,2048], Kb [4096,512], Vt [512,4096] (V transposed)
//   flash attention: 8 waves/block, wave = (head in group) x 32 q-rows, fixed-max exp2 softmax
//   gemm: out = Ab @ Wo + bo (fp32)

typedef __attribute__((ext_vector_type(8))) short short8;
typedef __attribute__((ext_vector_type(4))) short short4v;
typedef __attribute__((ext_vector_type(4))) float float4v;

#define C1F 0.12751743f   // (1/sqrt(128)) * log2(e)
#define B0F -16.0f        // fixed max offset in log2 units (scores bounded ~|8| log2 units)

#if defined(__has_builtin) && __has_builtin(__builtin_amdgcn_exp2f)
#define EXP2(x) __builtin_amdgcn_exp2f(x)
#else
#define EXP2(x) exp2f(x)
#endif

__device__ __forceinline__ short f2bf(float x) {
    __hip_bfloat16 h = __float2bfloat16(x);
    short s; __builtin_memcpy(&s, &h, sizeof(s)); return s;
}

__device__ __forceinline__ void gl16(const short* g, short* l) {
    __builtin_amdgcn_global_load_lds(
        (const __attribute__((address_space(1))) void*)g,
        (__attribute__((address_space(3))) void*)l, 16, 0, 0);
}

// ---------------- fp32 -> bf16 elementwise ----------------
__global__ __launch_bounds__(256) void cvt_bf16_kernel(const float* __restrict__ in,
                                                       short* __restrict__ out, int n) {
    int i = (blockIdx.x * 256 + threadIdx.x) * 4;
    if (i >= n) return;
    float4 v = *(const float4*)(in + i);
    short4v o;
    o[0] = f2bf(v.x); o[1] = f2bf(v.y); o[2] = f2bf(v.z); o[3] = f2bf(v.w);
    *(short4v*)(out + i) = o;
}

// ---------------- W[K,N] fp32 -> Wt[N,K] bf16 ----------------
__global__ __launch_bounds__(256) void transpose_cvt_kernel(const float* __restrict__ W,
                                                            short* __restrict__ Wt,
                                                            int K, int N) {
    __shared__ float tile[32][33];
    int n0 = blockIdx.x * 32, k0 = blockIdx.y * 32;
    int tx = threadIdx.x & 31, ty = threadIdx.x >> 5;
#pragma unroll
    for (int i = 0; i < 4; ++i) {
        int kk = ty + i * 8;
        tile[kk][tx] = W[(size_t)(k0 + kk) * N + n0 + tx];
    }
    __syncthreads();
#pragma unroll
    for (int i = 0; i < 4; ++i) {
        int nn = ty + i * 8;
        Wt[(size_t)(n0 + nn) * K + k0 + tx] = f2bf(tile[tx][nn]);
    }
}

// ---------------- GEMM (m97 pattern): C = A[M,K] @ Bt[N,K]^T + bias ----------------
// 128x128 tile, BK=32, 4 waves. global_load_lds width-16 staging.
// mode 0: fused QKV epilogue (Q->O0 [*,2048], K->O1 [*,512], V->O2 transposed [512,4096])
// mode 1: fp32 out Of [*,2048] + b0
__global__ __launch_bounds__(256) void gemm_dma_kernel(
    const short* __restrict__ A, const short* __restrict__ Bt,
    const float* __restrict__ b0, const float* __restrict__ b1, const float* __restrict__ b2,
    short* __restrict__ O0, short* __restrict__ O1, short* __restrict__ O2,
    float* __restrict__ Of, int K, int mode) {
    __shared__ short As[128 * 32];
    __shared__ short Bs[128 * 32];
    const int t = threadIdx.x, lane = t & 63, w = t >> 6;
    const int l15 = lane & 15, quad = lane >> 4;
    const int wm = (w & 1) * 64, wn = (w >> 1) * 64;
    const int m0 = blockIdx.y * 128, n0 = blockIdx.x * 128;
    const int r4 = lane >> 2, c8 = (lane & 3) * 8;
    const short* ga = A + (size_t)(m0 + w * 16 + r4) * K + c8;
    const short* gb = Bt + (size_t)(n0 + w * 16 + r4) * K + c8;
    short* lA = As + (w * 16) * 32;   // wave-uniform LDS base, dst = base + lane*16B
    short* lB = Bs + (w * 16) * 32;

    float4v acc[4][4] = {};

    for (int k0 = 0; k0 < K; k0 += 32) {
        gl16(ga + k0, lA);
        gl16(ga + (size_t)64 * K + k0, lA + 64 * 32);
        gl16(gb + k0, lB);
        gl16(gb + (size_t)64 * K + k0, lB + 64 * 32);
        __syncthreads();   // drains vmcnt -> staging visible
        short8 af[4], bfr[4];
#pragma unroll
        for (int i = 0; i < 4; ++i)
            af[i] = *(const short8*)(As + (wm + i * 16 + l15) * 32 + quad * 8);
#pragma unroll
        for (int j = 0; j < 4; ++j)
            bfr[j] = *(const short8*)(Bs + (wn + j * 16 + l15) * 32 + quad * 8);
#pragma unroll
        for (int i = 0; i < 4; ++i)
#pragma unroll
            for (int j = 0; j < 4; ++j)
                acc[i][j] = __builtin_amdgcn_mfma_f32_16x16x32_bf16(af[i], bfr[j], acc[i][j], 0, 0, 0);
        __syncthreads();   // all reads done before next staging overwrite
    }

#pragma unroll
    for (int i = 0; i < 4; ++i) {
#pragma unroll
        for (int j = 0; j < 4; ++j) {
            const int col = n0 + wn + j * 16 + l15;
            const int row0 = m0 + wm + i * 16 + quad * 4;
            if (mode == 1) {
                const float bc = b0[col];
#pragma unroll
                for (int r = 0; r < 4; ++r)
                    Of[(size_t)(row0 + r) * 2048 + col] = acc[i][j][r] + bc;
            } else if (col < 2048) {
                const float bc = b0[col];
#pragma unroll
                for (int r = 0; r < 4; ++r)
                    O0[(size_t)(row0 + r) * 2048 + col] = f2bf(acc[i][j][r] + bc);
            } else if (col < 2560) {
                const int c = col - 2048;
                const float bc = b1[c];
#pragma unroll
                for (int r = 0; r < 4; ++r)
                    O1[(size_t)(row0 + r) * 512 + c] = f2bf(acc[i][j][r] + bc);
            } else {
                const int c = col - 2560;
                const float bc = b2[c];
#pragma unroll
                for (int r = 0; r < 4; ++r)
                    O2[(size_t)c * 4096 + row0 + r] = f2bf(acc[i][j][r] + bc);
            }
        }
    }
}

// ---------------- Flash attention, fixed-max exp2 softmax ----------------
// grid (S/64, G, B), 512 threads = 8 waves. Wave w: head = g + 4*(w&3) (jnp.tile
// semantics: group = h % 4), q-rows = qt*64 + (w>>2)*32 .. +32.
// K/V tile (64 keys) staged once per block serves all 4 heads of the group.
__global__ __launch_bounds__(512, 2) void flash_kernel(
    const short* __restrict__ Qb, const short* __restrict__ Kb,
    const short* __restrict__ Vt, const int* __restrict__ mask,
    short* __restrict__ Ab) {
    __shared__ short Ks[64 * 136];   // keys x d, stride pad 136
    __shared__ short Vs[128 * 72];   // d x keys, stride pad 72
    __shared__ short Ps[8 * 32 * 72];// per-wave P slices (32 q-rows x 64 keys)
    __shared__ float mb[64];

    const int t = threadIdx.x;
    const int lane = t & 63, w = t >> 6;
    const int l15 = lane & 15, quad = lane >> 4;
    const int qt = blockIdx.x, g = blockIdx.y, b = blockIdx.z;
    const int h = g + 4 * (w & 3);
    const int q0 = qt * 64 + (w >> 2) * 32;

    // Q fragments: 2 m-frags x 4 k-steps
    short8 qf[2][4];
#pragma unroll
    for (int mi = 0; mi < 2; ++mi)
#pragma unroll
        for (int ks = 0; ks < 4; ++ks)
            qf[mi][ks] = *(const short8*)(Qb + (size_t)(b * 2048 + q0 + mi * 16 + l15) * 2048
                                          + h * 128 + ks * 32 + quad * 8);

    float4v o[2][8] = {};
    float rsum[2][4] = {};
    short* PsW = Ps + w * (32 * 72);

    const int kR = t >> 4, kC = (t & 15) * 8;  // K stage: rows kR, kR+32
    const int vR = t >> 3, vC = (t & 7) * 8;   // V stage: rows vR, vR+64
    const short* kg = Kb + (size_t)(b * 2048 + kR) * 512 + g * 128 + kC;
    const short* vg = Vt + (size_t)(g * 128 + vR) * 4096 + (size_t)b * 2048 + vC;

    for (int kt = 0; kt < 32; ++kt) {
        const int kb = kt * 64;
        short8 k0v = *(const short8*)(kg + (size_t)kb * 512);
        short8 k1v = *(const short8*)(kg + (size_t)(kb + 32) * 512);
        short8 v0v = *(const short8*)(vg + kb);
        short8 v1v = *(const short8*)(vg + (size_t)64 * 4096 + kb);
        float mv = 0.f;
        if (t < 64) mv = mask[b * 2048 + kb + t] ? B0F : -1e30f;
        __syncthreads();   // all waves finished PV reads of previous tile
        *(short8*)(Ks + kR * 136 + kC) = k0v;
        *(short8*)(Ks + (kR + 32) * 136 + kC) = k1v;
        *(short8*)(Vs + vR * 72 + vC) = v0v;
        *(short8*)(Vs + (vR + 64) * 72 + vC) = v1v;
        if (t < 64) mb[t] = mv;
        __syncthreads();

        // S = Q @ K^T (raw dot; scale folded into exp2)
        float4v s[2][4] = {};
#pragma unroll
        for (int ks = 0; ks < 4; ++ks)
#pragma unroll
            for (int j = 0; j < 4; ++j) {
                short8 bk = *(const short8*)(Ks + (j * 16 + l15) * 136 + ks * 32 + quad * 8);
                s[0][j] = __builtin_amdgcn_mfma_f32_16x16x32_bf16(qf[0][ks], bk, s[0][j], 0, 0, 0);
                s[1][j] = __builtin_amdgcn_mfma_f32_16x16x32_bf16(qf[1][ks], bk, s[1][j], 0, 0, 0);
            }
        // p = 2^(s*C1 + mb[col])   (mb = B0F or -1e30); accumulate row sums linearly
#pragma unroll
        for (int mi = 0; mi < 2; ++mi)
#pragma unroll
            for (int j = 0; j < 4; ++j) {
                const float mbias = mb[j * 16 + l15];
#pragma unroll
                for (int r = 0; r < 4; ++r) {
                    float p = EXP2(fmaf(s[mi][j][r], C1F, mbias));
                    rsum[mi][r] += p;
                    PsW[(mi * 16 + quad * 4 + r) * 72 + j * 16 + l15] = f2bf(p);
                }
            }
        // O += P @ V (P round-trips LDS per-wave; no barrier needed)
#pragma unroll
        for (int ks2 = 0; ks2 < 2; ++ks2) {
            short8 pa0 = *(const short8*)(PsW + l15 * 72 + ks2 * 32 + quad * 8);
            short8 pa1 = *(const short8*)(PsW + (16 + l15) * 72 + ks2 * 32 + quad * 8);
#pragma unroll
            for (int jj = 0; jj < 8; ++jj) {
                short8 bv = *(const short8*)(Vs + (jj * 16 + l15) * 72 + ks2 * 32 + quad * 8);
                o[0][jj] = __builtin_amdgcn_mfma_f32_16x16x32_bf16(pa0, bv, o[0][jj], 0, 0, 0);
                o[1][jj] = __builtin_amdgcn_mfma_f32_16x16x32_bf16(pa1, bv, o[1][jj], 0, 0, 0);
            }
        }
    }

    // normalize: reduce rsum across the 16 l15 lanes (once), then store
    float rinv[2][4];
#pragma unroll
    for (int mi = 0; mi < 2; ++mi)
#pragma unroll
        for (int r = 0; r < 4; ++r) {
            float v = rsum[mi][r];
            v += __shfl_xor(v, 1, 64); v += __shfl_xor(v, 2, 64);
            v += __shfl_xor(v, 4, 64); v += __shfl_xor(v, 8, 64);
            rinv[mi][r] = (v > 0.f) ? 1.f / v : 0.f;
        }
    const size_t ob = (size_t)(b * 2048 + q0) * 2048 + h * 128;
#pragma unroll
    for (int mi = 0; mi < 2; ++mi)
#pragma unroll
        for (int jj = 0; jj < 8; ++jj)
#pragma unroll
            for (int r = 0; r < 4; ++r)
                Ab[ob + (size_t)(mi * 16 + quad * 4 + r) * 2048 + jj * 16 + l15] =
                    f2bf(o[mi][jj][r] * rinv[mi][r]);
}

extern "C" void kernel_launch(void* const* d_in, const int* in_sizes, int n_in,
                              void* d_out, int out_size, void* d_ws, size_t ws_size,
                              hipStream_t stream) {
    (void)in_sizes; (void)n_in; (void)out_size; (void)ws_size;
    const float* X  = (const float*)d_in[0];
    const int* mask = (const int*)d_in[1];
    const float* Wq = (const float*)d_in[2];
    const float* bq = (const float*)d_in[3];
    const float* Wk = (const float*)d_in[4];
    const float* bk = (const float*)d_in[5];
    const float* Wv = (const float*)d_in[6];
    const float* bv = (const float*)d_in[7];
    const float* Wo = (const float*)d_in[8];
    const float* bo = (const float*)d_in[9];
    float* out = (float*)d_out;

    char* ws = (char*)d_ws;
    short* Xb     = (short*)(ws + 0);          // 16,777,216 B (reused as Ab)
    short* WqkvT  = (short*)(ws + 16777216);   // 12,582,912 B [3072,2048]
    short* Wot    = (short*)(ws + 29360128);   //  8,388,608 B
    short* Qb     = (short*)(ws + 37748736);   // 16,777,216 B
    short* Kb     = (short*)(ws + 54525952);   //  4,194,304 B
    short* Vt     = (short*)(ws + 58720256);   //  4,194,304 B
    short* Ab     = Xb;

    const int M = 4096, HID = 2048, KV = 512;

    cvt_bf16_kernel<<<8192, 256, 0, stream>>>(X, Xb, M * HID);
    transpose_cvt_kernel<<<dim3(64, 64), 256, 0, stream>>>(Wq, WqkvT, HID, HID);
    transpose_cvt_kernel<<<dim3(16, 64), 256, 0, stream>>>(Wk, WqkvT + (size_t)2048 * 2048, HID, KV);
    transpose_cvt_kernel<<<dim3(16, 64), 256, 0, stream>>>(Wv, WqkvT + (size_t)2560 * 2048, HID, KV);
    transpose_cvt_kernel<<<dim3(64, 64), 256, 0, stream>>>(Wo, Wot, HID, HID);

    // fused Q|K|V projection: N = 3072
    gemm_dma_kernel<<<dim3(24, 32), 256, 0, stream>>>(
        Xb, WqkvT, bq, bk, bv, Qb, Kb, Vt, nullptr, HID, 0);

    flash_kernel<<<dim3(32, 4, 2), 512, 0, stream>>>(Qb, Kb, Vt, mask, Ab);

    gemm_dma_kernel<<<dim3(16, 32), 256, 0, stream>>>(
        Ab, Wot, bo, nullptr, nullptr, nullptr, nullptr, nullptr, out, HID, 1);
}